// Round 1
// baseline (674.207 us; speedup 1.0000x reference)
//
#include <hip/hip_runtime.h>
#include <math.h>

#define BLK 256
#define SCAN_CHUNK 1024

// ---------------- CSR build ----------------

__global__ void count_deg_kernel(const int* __restrict__ dst, int* __restrict__ deg, int E){
  int e = blockIdx.x*blockDim.x + threadIdx.x;
  if (e < E) atomicAdd(&deg[dst[e]], 1);
}

__global__ void dinv_kernel(const int* __restrict__ deg, float* __restrict__ dinv, int N){
  int i = blockIdx.x*blockDim.x + threadIdx.x;
  if (i < N) dinv[i] = rsqrtf((float)(deg[i] + 1));   // +1 = self-loop
}

__global__ void scanA_kernel(const int* __restrict__ deg, int* __restrict__ rowptr,
                             int* __restrict__ bsum, int N){
  __shared__ int sd[BLK];
  int tid = threadIdx.x;
  int base = blockIdx.x * SCAN_CHUNK;
  int vals[4]; int tsum = 0;
  #pragma unroll
  for (int q=0;q<4;q++){
    int idx = base + tid*4 + q;
    int v = (idx < N) ? (deg[idx] + 1) : 0;
    vals[q] = v; tsum += v;
  }
  sd[tid] = tsum; __syncthreads();
  for (int off=1; off<BLK; off<<=1){
    int v = (tid >= off) ? sd[tid-off] : 0;
    __syncthreads();
    sd[tid] += v;
    __syncthreads();
  }
  int run = sd[tid] - tsum;    // exclusive prefix of this thread
  #pragma unroll
  for (int q=0;q<4;q++){
    run += vals[q];
    int idx = base + tid*4 + q;
    if (idx < N) rowptr[idx+1] = run;   // inclusive within chunk
  }
  if (tid == BLK-1) bsum[blockIdx.x] = sd[BLK-1];
}

__global__ void scanB_kernel(int* bsum, int B){
  __shared__ int sd[BLK];
  int tid = threadIdx.x;
  int v0 = (tid < B) ? bsum[tid] : 0;
  sd[tid] = v0; __syncthreads();
  for (int off=1; off<BLK; off<<=1){
    int v = (tid>=off) ? sd[tid-off] : 0;
    __syncthreads();
    sd[tid] += v;
    __syncthreads();
  }
  if (tid < B) bsum[tid] = sd[tid] - v0;   // exclusive block offsets
}

__global__ void scanC_kernel(int* rowptr, const int* __restrict__ bsum, int N){
  int i = blockIdx.x*blockDim.x + threadIdx.x;
  if (i == 0) rowptr[0] = 0;
  if (i < N) rowptr[i+1] += bsum[i / SCAN_CHUNK];
}

__global__ void fill_kernel(const int* __restrict__ src, const int* __restrict__ dst,
                            const int* __restrict__ rowptr, int* __restrict__ cursor,
                            const float* __restrict__ dinv,
                            int* __restrict__ col, float* __restrict__ wgt, int E, int N){
  int t = blockIdx.x*blockDim.x + threadIdx.x;
  if (t >= E + N) return;
  int s, d;
  if (t < E){ s = src[t]; d = dst[t]; } else { s = t - E; d = s; }  // self-loops appended
  int pos = rowptr[d] + atomicAdd(&cursor[d], 1);
  col[pos] = s;
  wgt[pos] = dinv[s] * dinv[d];
}

// ---------------- GEMM1: [M,256] x [256,128] -> [M,128], fp32 ----------------
// 128x128 tile, 256 threads, 8x8 micro-tile, K-chunks of 16.

#define GM_TM 128
#define GM_TK 16
#define GM_TN 128
#define XS_LD (GM_TM + 4)   // pad 4 floats: keeps float4 alignment, breaks 4-way write conflict

__global__ __launch_bounds__(256, 2)
void gemm1_kernel(const float* __restrict__ X, const float* __restrict__ W,
                  float* __restrict__ Y, int M){
  __shared__ float xs[GM_TK][XS_LD];   // xs[k][m]
  __shared__ float ws[GM_TK][GM_TN];   // ws[k][n]
  const int tid = threadIdx.x;
  const int tx = tid & 15;     // col group (8 cols)
  const int ty = tid >> 4;     // row group (8 rows)
  const int row0 = blockIdx.x * GM_TM;

  float acc[8][8];
  #pragma unroll
  for (int i=0;i<8;i++){
    #pragma unroll
    for (int j=0;j<8;j++) acc[i][j] = 0.f;
  }

  for (int k0 = 0; k0 < 256; k0 += GM_TK){
    // X tile: 128 rows x 16 k = 512 float4 loads, 2 per thread, transpose into xs[k][m]
    #pragma unroll
    for (int i=0;i<2;i++){
      int l = i*256 + tid;
      int q = l & 3;          // k-quad
      int m = l >> 2;         // row in tile
      int gr = row0 + m;
      float4 v = make_float4(0.f,0.f,0.f,0.f);
      if (gr < M) v = *(const float4*)(X + (size_t)gr*256 + k0 + q*4);
      xs[q*4+0][m] = v.x; xs[q*4+1][m] = v.y; xs[q*4+2][m] = v.z; xs[q*4+3][m] = v.w;
    }
    // W tile: 16 k x 128 n = 512 float4 loads
    #pragma unroll
    for (int i=0;i<2;i++){
      int l = i*256 + tid;
      int n4 = l & 31;
      int k  = l >> 5;
      *(float4*)&ws[k][n4*4] = *(const float4*)(W + (size_t)(k0+k)*128 + n4*4);
    }
    __syncthreads();
    #pragma unroll
    for (int kk=0; kk<GM_TK; kk++){
      float a[8], b[8];
      *(float4*)&a[0] = *(const float4*)&xs[kk][ty*8];
      *(float4*)&a[4] = *(const float4*)&xs[kk][ty*8+4];
      *(float4*)&b[0] = *(const float4*)&ws[kk][tx*8];
      *(float4*)&b[4] = *(const float4*)&ws[kk][tx*8+4];
      #pragma unroll
      for (int i=0;i<8;i++){
        #pragma unroll
        for (int j=0;j<8;j++) acc[i][j] += a[i]*b[j];
      }
    }
    __syncthreads();
  }
  #pragma unroll
  for (int i=0;i<8;i++){
    int gr = row0 + ty*8 + i;
    if (gr < M){
      *(float4*)(Y + (size_t)gr*128 + tx*8)     = make_float4(acc[i][0],acc[i][1],acc[i][2],acc[i][3]);
      *(float4*)(Y + (size_t)gr*128 + tx*8 + 4) = make_float4(acc[i][4],acc[i][5],acc[i][6],acc[i][7]);
    }
  }
}

// ---------------- Aggregation layer 1: wave per node, 128 feats, +bias, ReLU ----------------

__global__ __launch_bounds__(256)
void agg1_kernel(const float* __restrict__ H1, const int* __restrict__ rowptr,
                 const int* __restrict__ col, const float* __restrict__ wgt,
                 const float* __restrict__ b1, float* __restrict__ out, int N){
  int wave = blockIdx.x * (blockDim.x >> 6) + (threadIdx.x >> 6);
  int lane = threadIdx.x & 63;
  if (wave >= N) return;
  float acc0 = 0.f, acc1 = 0.f;
  int s = rowptr[wave], e = rowptr[wave+1];
  for (int j = s; j < e; j++){
    int c = col[j];
    float w = wgt[j];
    const float* h = H1 + (size_t)c*128;
    acc0 += w * h[lane];
    acc1 += w * h[lane+64];
  }
  float r0 = acc0 + b1[lane];
  float r1 = acc1 + b1[lane+64];
  out[(size_t)wave*128 + lane]      = r0 > 0.f ? r0 : 0.f;
  out[(size_t)wave*128 + 64 + lane] = r1 > 0.f ? r1 : 0.f;
}

// ---------------- GEMM2: [M,128] x [128,10] -> [M,10] ----------------

__global__ __launch_bounds__(256)
void gemm2_kernel(const float* __restrict__ A, const float* __restrict__ W2,
                  float* __restrict__ Y, int M){
  __shared__ float w2s[128*10];
  for (int i = threadIdx.x; i < 128*10; i += blockDim.x) w2s[i] = W2[i];
  __syncthreads();
  int r = blockIdx.x*blockDim.x + threadIdx.x;
  if (r >= M) return;
  float acc[10];
  #pragma unroll
  for (int c=0;c<10;c++) acc[c] = 0.f;
  const float* a = A + (size_t)r*128;
  for (int k=0;k<128;k+=4){
    float4 v = *(const float4*)(a + k);
    #pragma unroll
    for (int c=0;c<10;c++){
      acc[c] += v.x*w2s[(k+0)*10+c] + v.y*w2s[(k+1)*10+c]
              + v.z*w2s[(k+2)*10+c] + v.w*w2s[(k+3)*10+c];
    }
  }
  #pragma unroll
  for (int c=0;c<10;c++) Y[(size_t)r*10 + c] = acc[c];
}

// ---------------- Aggregation layer 2 + bias + log_softmax ----------------

__global__ __launch_bounds__(256)
void agg2_softmax_kernel(const float* __restrict__ H2, const int* __restrict__ rowptr,
                         const int* __restrict__ col, const float* __restrict__ wgt,
                         const float* __restrict__ b2, float* __restrict__ out, int N){
  int i = blockIdx.x*blockDim.x + threadIdx.x;
  if (i >= N) return;
  float acc[10];
  #pragma unroll
  for (int c=0;c<10;c++) acc[c] = 0.f;
  int s = rowptr[i], e = rowptr[i+1];
  for (int j = s; j < e; j++){
    int c = col[j];
    float w = wgt[j];
    const float* h = H2 + (size_t)c*10;
    #pragma unroll
    for (int f=0;f<10;f++) acc[f] += w * h[f];
  }
  #pragma unroll
  for (int f=0;f<10;f++) acc[f] += b2[f];
  float m = acc[0];
  #pragma unroll
  for (int f=1;f<10;f++) m = fmaxf(m, acc[f]);
  float sum = 0.f;
  #pragma unroll
  for (int f=0;f<10;f++) sum += expf(acc[f] - m);
  float lg = m + logf(sum);
  #pragma unroll
  for (int f=0;f<10;f++) out[(size_t)i*10 + f] = acc[f] - lg;
}

// ---------------- launch ----------------

extern "C" void kernel_launch(void* const* d_in, const int* in_sizes, int n_in,
                              void* d_out, int out_size, void* d_ws, size_t ws_size,
                              hipStream_t stream){
  const float* x    = (const float*)d_in[0];
  const int*   ei   = (const int*)d_in[1];
  const float* W1   = (const float*)d_in[2];
  const float* b1   = (const float*)d_in[3];
  const float* W2   = (const float*)d_in[4];
  const float* b2   = (const float*)d_in[5];
  float* out = (float*)d_out;

  const int N = in_sizes[0] / 256;   // 100000
  const int E = in_sizes[1] / 2;     // 1600000
  const int NNZ = E + N;
  const int* src = ei;
  const int* dst = ei + E;

  // workspace partition (256B aligned)
  char* ws = (char*)d_ws;
  size_t off = 0;
  auto alloc = [&](size_t bytes)->char*{
    char* p = ws + off;
    off = (off + bytes + 255) & ~(size_t)255;
    return p;
  };
  int*   deg    = (int*)  alloc((size_t)N*4);
  int*   cursor = (int*)  alloc((size_t)N*4);
  float* dinv   = (float*)alloc((size_t)N*4);
  int*   rowptr = (int*)  alloc((size_t)(N+1)*4);
  int*   bsum   = (int*)  alloc((size_t)BLK*4);
  int*   col    = (int*)  alloc((size_t)NNZ*4);
  float* wgt    = (float*)alloc((size_t)NNZ*4);
  float* h1     = (float*)alloc((size_t)N*128*4);
  float* r1     = (float*)alloc((size_t)N*128*4);
  float* h2     = (float*)alloc((size_t)N*10*4);
  (void)ws_size;

  hipMemsetAsync(deg,    0, (size_t)N*4, stream);
  hipMemsetAsync(cursor, 0, (size_t)N*4, stream);

  const int B = (N + SCAN_CHUNK - 1) / SCAN_CHUNK;

  count_deg_kernel<<<(E+BLK-1)/BLK, BLK, 0, stream>>>(dst, deg, E);
  dinv_kernel<<<(N+BLK-1)/BLK, BLK, 0, stream>>>(deg, dinv, N);
  scanA_kernel<<<B, BLK, 0, stream>>>(deg, rowptr, bsum, N);
  scanB_kernel<<<1, BLK, 0, stream>>>(bsum, B);
  scanC_kernel<<<(N+BLK-1)/BLK, BLK, 0, stream>>>(rowptr, bsum, N);
  fill_kernel<<<(NNZ+BLK-1)/BLK, BLK, 0, stream>>>(src, dst, rowptr, cursor, dinv, col, wgt, E, N);

  gemm1_kernel<<<(N+GM_TM-1)/GM_TM, 256, 0, stream>>>(x, W1, h1, N);
  agg1_kernel<<<(N+3)/4, 256, 0, stream>>>(h1, rowptr, col, wgt, b1, r1, N);
  gemm2_kernel<<<(N+BLK-1)/BLK, BLK, 0, stream>>>(r1, W2, h2, N);
  agg2_softmax_kernel<<<(N+BLK-1)/BLK, BLK, 0, stream>>>(h2, rowptr, col, wgt, b2, out, N);
}

// Round 3
// 564.007 us; speedup vs baseline: 1.1954x; 1.1954x over previous
//
#include <hip/hip_runtime.h>
#include <math.h>

#define BLK 256
#define SCAN_CHUNK 1024

typedef __attribute__((ext_vector_type(8))) short bf16x8;
typedef __attribute__((ext_vector_type(4))) float f32x4;

__device__ inline unsigned short f2b(float f){
  union { float f; unsigned int u; } v; v.f = f;
  unsigned int u = v.u;
  return (unsigned short)((u + 0x7FFF + ((u >> 16) & 1)) >> 16);
}
__device__ inline float b2f_lo(unsigned int u){
  union { unsigned int u; float f; } v; v.u = u << 16; return v.f;
}
__device__ inline float b2f_hi(unsigned int u){
  union { unsigned int u; float f; } v; v.u = u & 0xFFFF0000u; return v.f;
}

// ---------------- CSR build ----------------

__global__ void count_deg_kernel(const int* __restrict__ dst, int* __restrict__ deg, int E){
  int e = blockIdx.x*blockDim.x + threadIdx.x;
  if (e < E) atomicAdd(&deg[dst[e]], 1);
}

__global__ void dinv_kernel(const int* __restrict__ deg, float* __restrict__ dinv, int N){
  int i = blockIdx.x*blockDim.x + threadIdx.x;
  if (i < N) dinv[i] = rsqrtf((float)(deg[i] + 1));   // +1 = self-loop
}

__global__ void scanA_kernel(const int* __restrict__ deg, int* __restrict__ rowptr,
                             int* __restrict__ bsum, int N){
  __shared__ int sd[BLK];
  int tid = threadIdx.x;
  int base = blockIdx.x * SCAN_CHUNK;
  int vals[4]; int tsum = 0;
  #pragma unroll
  for (int q=0;q<4;q++){
    int idx = base + tid*4 + q;
    int v = (idx < N) ? (deg[idx] + 1) : 0;
    vals[q] = v; tsum += v;
  }
  sd[tid] = tsum; __syncthreads();
  for (int off=1; off<BLK; off<<=1){
    int v = (tid >= off) ? sd[tid-off] : 0;
    __syncthreads();
    sd[tid] += v;
    __syncthreads();
  }
  int run = sd[tid] - tsum;
  #pragma unroll
  for (int q=0;q<4;q++){
    run += vals[q];
    int idx = base + tid*4 + q;
    if (idx < N) rowptr[idx+1] = run;
  }
  if (tid == BLK-1) bsum[blockIdx.x] = sd[BLK-1];
}

__global__ void scanB_kernel(int* bsum, int B){
  __shared__ int sd[BLK];
  int tid = threadIdx.x;
  int v0 = (tid < B) ? bsum[tid] : 0;
  sd[tid] = v0; __syncthreads();
  for (int off=1; off<BLK; off<<=1){
    int v = (tid>=off) ? sd[tid-off] : 0;
    __syncthreads();
    sd[tid] += v;
    __syncthreads();
  }
  if (tid < B) bsum[tid] = sd[tid] - v0;
}

__global__ void scanC_kernel(int* rowptr, const int* __restrict__ bsum, int N){
  int i = blockIdx.x*blockDim.x + threadIdx.x;
  if (i == 0) rowptr[0] = 0;
  if (i < N) rowptr[i+1] += bsum[i / SCAN_CHUNK];
}

__global__ void fill_kernel(const int* __restrict__ src, const int* __restrict__ dst,
                            const int* __restrict__ rowptr, int* __restrict__ cursor,
                            const float* __restrict__ dinv,
                            int2* __restrict__ colw, int E, int N){
  int t = blockIdx.x*blockDim.x + threadIdx.x;
  if (t >= E + N) return;
  int s, d;
  if (t < E){ s = src[t]; d = dst[t]; } else { s = t - E; d = s; }
  int pos = rowptr[d] + atomicAdd(&cursor[d], 1);
  int2 v; v.x = s; v.y = __float_as_int(dinv[s] * dinv[d]);
  colw[pos] = v;
}

// ---------------- W1 transpose+cvt: [256][128] fp32 -> [128][256] bf16 ----------------

__global__ void wcvt_kernel(const float* __restrict__ W1, unsigned short* __restrict__ W1T){
  int t = blockIdx.x*blockDim.x + threadIdx.x;
  if (t < 256*128){
    int k = t >> 7, n = t & 127;
    W1T[n*256 + k] = f2b(W1[t]);
  }
}

// ---------------- GEMM1 (MFMA bf16): [M,256]x[256,128] -> h1 bf16 [M,128] ----------------
// block = 256 thr = 4 waves; 128 rows/block, full N=128; K-steps of 32.

#define XPAD 40   // bf16 elements per LDS row (32 + 8 pad): 80B row stride (16B-multiple)

__global__ __launch_bounds__(256)
void gemm1_mfma(const float* __restrict__ X, const unsigned short* __restrict__ W1T,
                unsigned short* __restrict__ H1B, int M){
  // aligned(16): short arrays get only 2B natural alignment; all accesses below are 16B vectors
  __shared__ __attribute__((aligned(16))) unsigned short xs[128*XPAD];   // [m][k]
  __shared__ __attribute__((aligned(16))) unsigned short wt[128*XPAD];   // [n][k]
  const int tid = threadIdx.x;
  const int wave = tid >> 6, lane = tid & 63;
  const int quad = lane >> 4, l16 = lane & 15;
  const int row0 = blockIdx.x * 128;

  f32x4 acc[2][8];
  #pragma unroll
  for (int i=0;i<2;i++)
    #pragma unroll
    for (int j=0;j<8;j++) acc[i][j] = (f32x4){0.f,0.f,0.f,0.f};

  const int r    = tid >> 1;      // staging row (x and w)
  const int half = tid & 1;

  for (int k0 = 0; k0 < 256; k0 += 32){
    // stage X tile: 128 rows x 32 k fp32 -> bf16
    {
      int gr = row0 + r;
      const float* xp = X + (size_t)gr*256 + k0 + half*16;
      unsigned short* xd = xs + r*XPAD + half*16;
      #pragma unroll
      for (int q=0;q<4;q++){
        float4 v = (gr < M) ? *(const float4*)(xp + q*4) : make_float4(0.f,0.f,0.f,0.f);
        ushort4 b;
        b.x = f2b(v.x); b.y = f2b(v.y); b.z = f2b(v.z); b.w = f2b(v.w);
        *(ushort4*)(xd + q*4) = b;
      }
    }
    // stage W tile: already [n][k] bf16 in global
    {
      const unsigned short* wp = W1T + r*256 + k0 + half*16;
      unsigned short* wd = wt + r*XPAD + half*16;
      uint4 a = *(const uint4*)wp;          // 8 bf16
      uint4 c = *(const uint4*)(wp + 8);    // 8 bf16
      *(uint4*)wd = a;
      *(uint4*)(wd + 8) = c;
    }
    __syncthreads();

    bf16x8 bfr[8];
    #pragma unroll
    for (int ct=0; ct<8; ct++)
      bfr[ct] = *(bf16x8*)(wt + (ct*16 + l16)*XPAD + quad*8);
    #pragma unroll
    for (int rt=0; rt<2; rt++){
      bf16x8 a = *(bf16x8*)(xs + (wave*32 + rt*16 + l16)*XPAD + quad*8);
      #pragma unroll
      for (int ct=0; ct<8; ct++)
        acc[rt][ct] = __builtin_amdgcn_mfma_f32_16x16x32_bf16(a, bfr[ct], acc[rt][ct], 0, 0, 0);
    }
    __syncthreads();
  }

  // epilogue: C/D layout col=lane&15, row=quad*4+reg
  #pragma unroll
  for (int rt=0; rt<2; rt++){
    int rbase = row0 + wave*32 + rt*16 + quad*4;
    #pragma unroll
    for (int rg=0; rg<4; rg++){
      int grow = rbase + rg;
      if (grow < M){
        #pragma unroll
        for (int ct=0; ct<8; ct++)
          H1B[(size_t)grow*128 + ct*16 + l16] = f2b(acc[rt][ct][rg]);
      }
    }
  }
}

// ---------------- fused agg1 (+bias,ReLU) + gemm2: wave per node -> h2 [N][12] ----------------

__global__ __launch_bounds__(256)
void agg1_gemm2_kernel(const unsigned short* __restrict__ H1B, const int* __restrict__ rowptr,
                       const int2* __restrict__ colw, const float* __restrict__ b1,
                       const float* __restrict__ W2, float* __restrict__ H2, int N){
  __shared__ __attribute__((aligned(16))) float w2s[128*11];   // pitch 11 (odd)
  for (int i = threadIdx.x; i < 128*10; i += blockDim.x){
    int rr = i / 10, cc = i - rr*10;
    w2s[rr*11 + cc] = W2[i];
  }
  __syncthreads();
  int node = blockIdx.x * 4 + (threadIdx.x >> 6);
  int lane = threadIdx.x & 63;
  if (node >= N) return;
  float acc0 = 0.f, acc1 = 0.f;
  int s = rowptr[node], e = rowptr[node+1];
  for (int j = s; j < e; j++){
    int2 cw = colw[j];
    float w = __int_as_float(cw.y);
    unsigned int u = *(const unsigned int*)(H1B + (size_t)cw.x*128 + lane*2);
    acc0 += w * b2f_lo(u);
    acc1 += w * b2f_hi(u);
  }
  float r0 = fmaxf(acc0 + b1[lane*2],     0.f);
  float r1 = fmaxf(acc1 + b1[lane*2 + 1], 0.f);
  float p[10];
  #pragma unroll
  for (int c=0;c<10;c++)
    p[c] = r0 * w2s[(lane*2)*11 + c] + r1 * w2s[(lane*2+1)*11 + c];
  #pragma unroll
  for (int m=1; m<64; m<<=1){
    #pragma unroll
    for (int c=0;c<10;c++) p[c] += __shfl_xor(p[c], m, 64);
  }
  if (lane == 0){
    float4* op = (float4*)(H2 + (size_t)node*12);
    op[0] = make_float4(p[0],p[1],p[2],p[3]);
    op[1] = make_float4(p[4],p[5],p[6],p[7]);
    op[2] = make_float4(p[8],p[9],0.f,0.f);
  }
}

// ---------------- agg2 + bias + log_softmax ----------------

__global__ __launch_bounds__(256)
void agg2_softmax_kernel(const float* __restrict__ H2, const int* __restrict__ rowptr,
                         const int2* __restrict__ colw, const float* __restrict__ b2,
                         float* __restrict__ out, int N){
  int i = blockIdx.x*blockDim.x + threadIdx.x;
  if (i >= N) return;
  float acc[10];
  #pragma unroll
  for (int c=0;c<10;c++) acc[c] = 0.f;
  int s = rowptr[i], e = rowptr[i+1];
  for (int j = s; j < e; j++){
    int2 cw = colw[j];
    float w = __int_as_float(cw.y);
    const float4* h = (const float4*)(H2 + (size_t)cw.x*12);
    float4 v0 = h[0], v1 = h[1], v2 = h[2];
    acc[0]+=w*v0.x; acc[1]+=w*v0.y; acc[2]+=w*v0.z; acc[3]+=w*v0.w;
    acc[4]+=w*v1.x; acc[5]+=w*v1.y; acc[6]+=w*v1.z; acc[7]+=w*v1.w;
    acc[8]+=w*v2.x; acc[9]+=w*v2.y;
  }
  #pragma unroll
  for (int f=0;f<10;f++) acc[f] += b2[f];
  float m = acc[0];
  #pragma unroll
  for (int f=1;f<10;f++) m = fmaxf(m, acc[f]);
  float sum = 0.f;
  #pragma unroll
  for (int f=0;f<10;f++) sum += expf(acc[f] - m);
  float lg = m + logf(sum);
  #pragma unroll
  for (int f=0;f<10;f++) out[(size_t)i*10 + f] = acc[f] - lg;
}

// ---------------- launch ----------------

extern "C" void kernel_launch(void* const* d_in, const int* in_sizes, int n_in,
                              void* d_out, int out_size, void* d_ws, size_t ws_size,
                              hipStream_t stream){
  const float* x    = (const float*)d_in[0];
  const int*   ei   = (const int*)d_in[1];
  const float* W1   = (const float*)d_in[2];
  const float* b1   = (const float*)d_in[3];
  const float* W2   = (const float*)d_in[4];
  const float* b2   = (const float*)d_in[5];
  float* out = (float*)d_out;

  const int N = in_sizes[0] / 256;   // 100000
  const int E = in_sizes[1] / 2;     // 1600000
  const int NNZ = E + N;
  const int* src = ei;
  const int* dst = ei + E;

  char* ws = (char*)d_ws;
  size_t off = 0;
  auto alloc = [&](size_t bytes)->char*{
    char* p = ws + off;
    off = (off + bytes + 255) & ~(size_t)255;
    return p;
  };
  int*   deg    = (int*)  alloc((size_t)N*4);
  int*   cursor = (int*)  alloc((size_t)N*4);
  float* dinv   = (float*)alloc((size_t)N*4);
  int*   rowptr = (int*)  alloc((size_t)(N+1)*4);
  int*   bsum   = (int*)  alloc((size_t)BLK*4);
  int2*  colw   = (int2*) alloc((size_t)NNZ*8);
  unsigned short* w1t = (unsigned short*)alloc((size_t)128*256*2);
  unsigned short* h1b = (unsigned short*)alloc((size_t)N*128*2);
  float* h2     = (float*)alloc((size_t)N*12*4);
  (void)ws_size;

  hipMemsetAsync(deg,    0, (size_t)N*4, stream);
  hipMemsetAsync(cursor, 0, (size_t)N*4, stream);

  const int B = (N + SCAN_CHUNK - 1) / SCAN_CHUNK;

  count_deg_kernel<<<(E+BLK-1)/BLK, BLK, 0, stream>>>(dst, deg, E);
  dinv_kernel<<<(N+BLK-1)/BLK, BLK, 0, stream>>>(deg, dinv, N);
  scanA_kernel<<<B, BLK, 0, stream>>>(deg, rowptr, bsum, N);
  scanB_kernel<<<1, BLK, 0, stream>>>(bsum, B);
  scanC_kernel<<<(N+BLK-1)/BLK, BLK, 0, stream>>>(rowptr, bsum, N);
  fill_kernel<<<(NNZ+BLK-1)/BLK, BLK, 0, stream>>>(src, dst, rowptr, cursor, dinv, colw, E, N);
  wcvt_kernel<<<(256*128+BLK-1)/BLK, BLK, 0, stream>>>(W1, w1t);

  gemm1_mfma<<<(N+127)/128, 256, 0, stream>>>(x, w1t, h1b, N);
  agg1_gemm2_kernel<<<(N+3)/4, 256, 0, stream>>>(h1b, rowptr, colw, b1, W2, h2, N);
  agg2_softmax_kernel<<<(N+BLK-1)/BLK, BLK, 0, stream>>>(h2, rowptr, colw, b2, out, N);
}

// Round 4
// 474.866 us; speedup vs baseline: 1.4198x; 1.1877x over previous
//
#include <hip/hip_runtime.h>
#include <math.h>

#define BLK 256
#define SCAN_CHUNK 1024

typedef __attribute__((ext_vector_type(8))) short bf16x8;
typedef __attribute__((ext_vector_type(4))) float f32x4;

__device__ inline unsigned short f2b(float f){
  union { float f; unsigned int u; } v; v.f = f;
  unsigned int u = v.u;
  return (unsigned short)((u + 0x7FFF + ((u >> 16) & 1)) >> 16);
}
__device__ inline float b2f_lo(unsigned int u){
  union { unsigned int u; float f; } v; v.u = u << 16; return v.f;
}
__device__ inline float b2f_hi(unsigned int u){
  union { unsigned int u; float f; } v; v.u = u & 0xFFFF0000u; return v.f;
}

// ---------------- CSR build ----------------

__global__ void count_deg_kernel(const int* __restrict__ dst, int* __restrict__ deg, int E){
  int e = blockIdx.x*blockDim.x + threadIdx.x;
  if (e < E) atomicAdd(&deg[dst[e]], 1);
}

__global__ void dinv_kernel(const int* __restrict__ deg, float* __restrict__ dinv, int N){
  int i = blockIdx.x*blockDim.x + threadIdx.x;
  if (i < N) dinv[i] = rsqrtf((float)(deg[i] + 1));   // +1 = self-loop
}

__global__ void scanA_kernel(const int* __restrict__ deg, int* __restrict__ rowptr,
                             int* __restrict__ bsum, int N){
  __shared__ int sd[BLK];
  int tid = threadIdx.x;
  int base = blockIdx.x * SCAN_CHUNK;
  int vals[4]; int tsum = 0;
  #pragma unroll
  for (int q=0;q<4;q++){
    int idx = base + tid*4 + q;
    int v = (idx < N) ? (deg[idx] + 1) : 0;
    vals[q] = v; tsum += v;
  }
  sd[tid] = tsum; __syncthreads();
  for (int off=1; off<BLK; off<<=1){
    int v = (tid >= off) ? sd[tid-off] : 0;
    __syncthreads();
    sd[tid] += v;
    __syncthreads();
  }
  int run = sd[tid] - tsum;
  #pragma unroll
  for (int q=0;q<4;q++){
    run += vals[q];
    int idx = base + tid*4 + q;
    if (idx < N) rowptr[idx+1] = run;
  }
  if (tid == BLK-1) bsum[blockIdx.x] = sd[BLK-1];
}

__global__ void scanB_kernel(int* bsum, int B){
  __shared__ int sd[BLK];
  int tid = threadIdx.x;
  int v0 = (tid < B) ? bsum[tid] : 0;
  sd[tid] = v0; __syncthreads();
  for (int off=1; off<BLK; off<<=1){
    int v = (tid>=off) ? sd[tid-off] : 0;
    __syncthreads();
    sd[tid] += v;
    __syncthreads();
  }
  if (tid < B) bsum[tid] = sd[tid] - v0;
}

__global__ void scanC_kernel(int* rowptr, const int* __restrict__ bsum, int N){
  int i = blockIdx.x*blockDim.x + threadIdx.x;
  if (i == 0) rowptr[0] = 0;
  if (i < N) rowptr[i+1] += bsum[i / SCAN_CHUNK];
}

__global__ void fill_kernel(const int* __restrict__ src, const int* __restrict__ dst,
                            const int* __restrict__ rowptr, int* __restrict__ cursor,
                            const float* __restrict__ dinv,
                            int2* __restrict__ colw, int E, int N){
  int t = blockIdx.x*blockDim.x + threadIdx.x;
  if (t >= E + N) return;
  int s, d;
  if (t < E){ s = src[t]; d = dst[t]; } else { s = t - E; d = s; }
  int pos = rowptr[d] + atomicAdd(&cursor[d], 1);
  int2 v; v.x = s; v.y = __float_as_int(dinv[s] * dinv[d]);
  colw[pos] = v;
}

// ---------------- W1 transpose+cvt: [256][128] fp32 -> [128][256] bf16 ----------------

__global__ void wcvt_kernel(const float* __restrict__ W1, unsigned short* __restrict__ W1T){
  int t = blockIdx.x*blockDim.x + threadIdx.x;
  if (t < 256*128){
    int k = t >> 7, n = t & 127;
    W1T[n*256 + k] = f2b(W1[t]);
  }
}

// ---------------- GEMM1 (MFMA bf16): [M,256]x[256,128] -> h1 bf16 [M,128] ----------------

#define XPAD 40   // bf16 elements per LDS row (32 + 8 pad): 80B row stride (16B-multiple)

__global__ __launch_bounds__(256)
void gemm1_mfma(const float* __restrict__ X, const unsigned short* __restrict__ W1T,
                unsigned short* __restrict__ H1B, int M){
  __shared__ __attribute__((aligned(16))) unsigned short xs[128*XPAD];   // [m][k]
  __shared__ __attribute__((aligned(16))) unsigned short wt[128*XPAD];   // [n][k]
  const int tid = threadIdx.x;
  const int wave = tid >> 6, lane = tid & 63;
  const int quad = lane >> 4, l16 = lane & 15;
  const int row0 = blockIdx.x * 128;

  f32x4 acc[2][8];
  #pragma unroll
  for (int i=0;i<2;i++)
    #pragma unroll
    for (int j=0;j<8;j++) acc[i][j] = (f32x4){0.f,0.f,0.f,0.f};

  const int r    = tid >> 1;
  const int half = tid & 1;

  for (int k0 = 0; k0 < 256; k0 += 32){
    {
      int gr = row0 + r;
      const float* xp = X + (size_t)gr*256 + k0 + half*16;
      unsigned short* xd = xs + r*XPAD + half*16;
      #pragma unroll
      for (int q=0;q<4;q++){
        float4 v = (gr < M) ? *(const float4*)(xp + q*4) : make_float4(0.f,0.f,0.f,0.f);
        ushort4 b;
        b.x = f2b(v.x); b.y = f2b(v.y); b.z = f2b(v.z); b.w = f2b(v.w);
        *(ushort4*)(xd + q*4) = b;
      }
    }
    {
      const unsigned short* wp = W1T + r*256 + k0 + half*16;
      unsigned short* wd = wt + r*XPAD + half*16;
      uint4 a = *(const uint4*)wp;
      uint4 c = *(const uint4*)(wp + 8);
      *(uint4*)wd = a;
      *(uint4*)(wd + 8) = c;
    }
    __syncthreads();

    bf16x8 bfr[8];
    #pragma unroll
    for (int ct=0; ct<8; ct++)
      bfr[ct] = *(bf16x8*)(wt + (ct*16 + l16)*XPAD + quad*8);
    #pragma unroll
    for (int rt=0; rt<2; rt++){
      bf16x8 a = *(bf16x8*)(xs + (wave*32 + rt*16 + l16)*XPAD + quad*8);
      #pragma unroll
      for (int ct=0; ct<8; ct++)
        acc[rt][ct] = __builtin_amdgcn_mfma_f32_16x16x32_bf16(a, bfr[ct], acc[rt][ct], 0, 0, 0);
    }
    __syncthreads();
  }

  #pragma unroll
  for (int rt=0; rt<2; rt++){
    int rbase = row0 + wave*32 + rt*16 + quad*4;
    #pragma unroll
    for (int rg=0; rg<4; rg++){
      int grow = rbase + rg;
      if (grow < M){
        #pragma unroll
        for (int ct=0; ct<8; ct++)
          H1B[(size_t)grow*128 + ct*16 + l16] = f2b(acc[rt][ct][rg]);
      }
    }
  }
}

// ---------------- agg1: wave/node gather (4-wide unrolled) + bias + ReLU -> bf16 r1 ----------------

__global__ __launch_bounds__(256)
void agg1_kernel(const unsigned short* __restrict__ H1B, const int* __restrict__ rowptr,
                 const int2* __restrict__ colw, const float* __restrict__ b1,
                 unsigned int* __restrict__ R1B, int N){
  int node = blockIdx.x * 4 + (threadIdx.x >> 6);
  int lane = threadIdx.x & 63;
  if (node >= N) return;
  int s = rowptr[node], e = rowptr[node+1];
  float a0=0.f,a1=0.f,b0=0.f,b1v=0.f,c0=0.f,c1=0.f,d0=0.f,d1=0.f;
  int j = s;
  for (; j+3 < e; j += 4){
    int2 A = colw[j], B = colw[j+1], C = colw[j+2], D = colw[j+3];
    unsigned uA = *(const unsigned*)(H1B + (size_t)A.x*128 + lane*2);
    unsigned uB = *(const unsigned*)(H1B + (size_t)B.x*128 + lane*2);
    unsigned uC = *(const unsigned*)(H1B + (size_t)C.x*128 + lane*2);
    unsigned uD = *(const unsigned*)(H1B + (size_t)D.x*128 + lane*2);
    float wA = __int_as_float(A.y), wB = __int_as_float(B.y);
    float wC = __int_as_float(C.y), wD = __int_as_float(D.y);
    a0 += wA*b2f_lo(uA); a1 += wA*b2f_hi(uA);
    b0 += wB*b2f_lo(uB); b1v+= wB*b2f_hi(uB);
    c0 += wC*b2f_lo(uC); c1 += wC*b2f_hi(uC);
    d0 += wD*b2f_lo(uD); d1 += wD*b2f_hi(uD);
  }
  for (; j < e; j++){
    int2 A = colw[j];
    unsigned uA = *(const unsigned*)(H1B + (size_t)A.x*128 + lane*2);
    float wA = __int_as_float(A.y);
    a0 += wA*b2f_lo(uA); a1 += wA*b2f_hi(uA);
  }
  float acc0 = (a0+b0)+(c0+d0);
  float acc1 = (a1+b1v)+(c1+d1);
  float r0 = fmaxf(acc0 + b1[lane*2],     0.f);
  float r1 = fmaxf(acc1 + b1[lane*2 + 1], 0.f);
  R1B[(size_t)node*64 + lane] = (unsigned)f2b(r0) | ((unsigned)f2b(r1) << 16);
}

// ---------------- GEMM2: [M,128]bf16 x [128,10] -> h2 [M,12] ----------------

__global__ __launch_bounds__(256)
void gemm2_kernel(const unsigned int* __restrict__ R1B, const float* __restrict__ W2,
                  float* __restrict__ H2, int M){
  __shared__ float w2s[128*10];   // reads below are wave-uniform -> broadcast, no conflicts
  for (int i = threadIdx.x; i < 128*10; i += blockDim.x) w2s[i] = W2[i];
  __syncthreads();
  int r = blockIdx.x*blockDim.x + threadIdx.x;
  if (r >= M) return;
  float acc[10];
  #pragma unroll
  for (int c=0;c<10;c++) acc[c] = 0.f;
  const unsigned int* row = R1B + (size_t)r*64;
  for (int k=0;k<64;k+=4){
    uint4 u = *(const uint4*)(row + k);
    float f0 = b2f_lo(u.x), f1 = b2f_hi(u.x);
    float f2 = b2f_lo(u.y), f3 = b2f_hi(u.y);
    float f4 = b2f_lo(u.z), f5 = b2f_hi(u.z);
    float f6 = b2f_lo(u.w), f7 = b2f_hi(u.w);
    #pragma unroll
    for (int c=0;c<10;c++){
      acc[c] += f0*w2s[(2*k+0)*10+c] + f1*w2s[(2*k+1)*10+c]
              + f2*w2s[(2*k+2)*10+c] + f3*w2s[(2*k+3)*10+c]
              + f4*w2s[(2*k+4)*10+c] + f5*w2s[(2*k+5)*10+c]
              + f6*w2s[(2*k+6)*10+c] + f7*w2s[(2*k+7)*10+c];
    }
  }
  float4* op = (float4*)(H2 + (size_t)r*12);
  op[0] = make_float4(acc[0],acc[1],acc[2],acc[3]);
  op[1] = make_float4(acc[4],acc[5],acc[6],acc[7]);
  op[2] = make_float4(acc[8],acc[9],0.f,0.f);
}

// ---------------- agg2 + bias + log_softmax (2-wide unrolled) ----------------

__global__ __launch_bounds__(256)
void agg2_softmax_kernel(const float* __restrict__ H2, const int* __restrict__ rowptr,
                         const int2* __restrict__ colw, const float* __restrict__ b2,
                         float* __restrict__ out, int N){
  int i = blockIdx.x*blockDim.x + threadIdx.x;
  if (i >= N) return;
  float acc[10], acc2[10];
  #pragma unroll
  for (int c=0;c<10;c++){ acc[c] = 0.f; acc2[c] = 0.f; }
  int s = rowptr[i], e = rowptr[i+1];
  int j = s;
  for (; j+1 < e; j += 2){
    int2 cwA = colw[j], cwB = colw[j+1];
    float wA = __int_as_float(cwA.y), wB = __int_as_float(cwB.y);
    const float4* hA = (const float4*)(H2 + (size_t)cwA.x*12);
    const float4* hB = (const float4*)(H2 + (size_t)cwB.x*12);
    float4 a0 = hA[0], a1 = hA[1], a2 = hA[2];
    float4 bq0 = hB[0], bq1 = hB[1], bq2 = hB[2];
    acc[0]+=wA*a0.x; acc[1]+=wA*a0.y; acc[2]+=wA*a0.z; acc[3]+=wA*a0.w;
    acc[4]+=wA*a1.x; acc[5]+=wA*a1.y; acc[6]+=wA*a1.z; acc[7]+=wA*a1.w;
    acc[8]+=wA*a2.x; acc[9]+=wA*a2.y;
    acc2[0]+=wB*bq0.x; acc2[1]+=wB*bq0.y; acc2[2]+=wB*bq0.z; acc2[3]+=wB*bq0.w;
    acc2[4]+=wB*bq1.x; acc2[5]+=wB*bq1.y; acc2[6]+=wB*bq1.z; acc2[7]+=wB*bq1.w;
    acc2[8]+=wB*bq2.x; acc2[9]+=wB*bq2.y;
  }
  if (j < e){
    int2 cw = colw[j];
    float w = __int_as_float(cw.y);
    const float4* h = (const float4*)(H2 + (size_t)cw.x*12);
    float4 v0 = h[0], v1 = h[1], v2 = h[2];
    acc[0]+=w*v0.x; acc[1]+=w*v0.y; acc[2]+=w*v0.z; acc[3]+=w*v0.w;
    acc[4]+=w*v1.x; acc[5]+=w*v1.y; acc[6]+=w*v1.z; acc[7]+=w*v1.w;
    acc[8]+=w*v2.x; acc[9]+=w*v2.y;
  }
  #pragma unroll
  for (int f=0;f<10;f++) acc[f] += acc2[f] + b2[f];
  float m = acc[0];
  #pragma unroll
  for (int f=1;f<10;f++) m = fmaxf(m, acc[f]);
  float sum = 0.f;
  #pragma unroll
  for (int f=0;f<10;f++) sum += expf(acc[f] - m);
  float lg = m + logf(sum);
  #pragma unroll
  for (int f=0;f<10;f++) out[(size_t)i*10 + f] = acc[f] - lg;
}

// ---------------- launch ----------------

extern "C" void kernel_launch(void* const* d_in, const int* in_sizes, int n_in,
                              void* d_out, int out_size, void* d_ws, size_t ws_size,
                              hipStream_t stream){
  const float* x    = (const float*)d_in[0];
  const int*   ei   = (const int*)d_in[1];
  const float* W1   = (const float*)d_in[2];
  const float* b1   = (const float*)d_in[3];
  const float* W2   = (const float*)d_in[4];
  const float* b2   = (const float*)d_in[5];
  float* out = (float*)d_out;

  const int N = in_sizes[0] / 256;   // 100000
  const int E = in_sizes[1] / 2;     // 1600000
  const int NNZ = E + N;
  const int* src = ei;
  const int* dst = ei + E;

  char* ws = (char*)d_ws;
  size_t off = 0;
  auto alloc = [&](size_t bytes)->char*{
    char* p = ws + off;
    off = (off + bytes + 255) & ~(size_t)255;
    return p;
  };
  int*   deg    = (int*)  alloc((size_t)N*4);
  int*   cursor = (int*)  alloc((size_t)N*4);
  float* dinv   = (float*)alloc((size_t)N*4);
  int*   rowptr = (int*)  alloc((size_t)(N+1)*4);
  int*   bsum   = (int*)  alloc((size_t)BLK*4);
  int2*  colw   = (int2*) alloc((size_t)NNZ*8);
  unsigned short* w1t = (unsigned short*)alloc((size_t)128*256*2);
  unsigned short* h1b = (unsigned short*)alloc((size_t)N*128*2);
  unsigned int*   r1b = (unsigned int*)  alloc((size_t)N*64*4);
  float* h2     = (float*)alloc((size_t)N*12*4);
  (void)ws_size;

  hipMemsetAsync(deg,    0, (size_t)N*4, stream);
  hipMemsetAsync(cursor, 0, (size_t)N*4, stream);

  const int B = (N + SCAN_CHUNK - 1) / SCAN_CHUNK;

  count_deg_kernel<<<(E+BLK-1)/BLK, BLK, 0, stream>>>(dst, deg, E);
  dinv_kernel<<<(N+BLK-1)/BLK, BLK, 0, stream>>>(deg, dinv, N);
  scanA_kernel<<<B, BLK, 0, stream>>>(deg, rowptr, bsum, N);
  scanB_kernel<<<1, BLK, 0, stream>>>(bsum, B);
  scanC_kernel<<<(N+BLK-1)/BLK, BLK, 0, stream>>>(rowptr, bsum, N);
  fill_kernel<<<(NNZ+BLK-1)/BLK, BLK, 0, stream>>>(src, dst, rowptr, cursor, dinv, colw, E, N);
  wcvt_kernel<<<(256*128+BLK-1)/BLK, BLK, 0, stream>>>(W1, w1t);

  gemm1_mfma<<<(N+127)/128, 256, 0, stream>>>(x, w1t, h1b, N);
  agg1_kernel<<<(N+3)/4, 256, 0, stream>>>(h1b, rowptr, colw, b1, r1b, N);
  gemm2_kernel<<<(N+BLK-1)/BLK, BLK, 0, stream>>>(r1b, W2, h2, N);
  agg2_softmax_kernel<<<(N+BLK-1)/BLK, BLK, 0, stream>>>(h2, rowptr, colw, b2, out, N);
}

// Round 5
// 418.601 us; speedup vs baseline: 1.6106x; 1.1344x over previous
//
#include <hip/hip_runtime.h>
#include <math.h>

#define BLK 256
#define SCAN_CHUNK 1024

typedef __attribute__((ext_vector_type(8))) short bf16x8;
typedef __attribute__((ext_vector_type(4))) float f32x4;

__device__ inline unsigned short f2b(float f){
  union { float f; unsigned int u; } v; v.f = f;
  unsigned int u = v.u;
  return (unsigned short)((u + 0x7FFF + ((u >> 16) & 1)) >> 16);
}
__device__ inline float b2f_lo(unsigned int u){
  union { unsigned int u; float f; } v; v.u = u << 16; return v.f;
}
__device__ inline float b2f_hi(unsigned int u){
  union { unsigned int u; float f; } v; v.u = u & 0xFFFF0000u; return v.f;
}

// ---------------- CSR build ----------------
// count phase: atomicAdd returns the within-node slot -> no second atomic pass
__global__ void count_deg_kernel(const int* __restrict__ dst, int* __restrict__ deg,
                                 int* __restrict__ eslot, int E){
  int e = blockIdx.x*blockDim.x + threadIdx.x;
  if (e < E) eslot[e] = atomicAdd(&deg[dst[e]], 1);
}

__global__ void dinv_kernel(const int* __restrict__ deg, float* __restrict__ dinv, int N){
  int i = blockIdx.x*blockDim.x + threadIdx.x;
  if (i < N) dinv[i] = rsqrtf((float)(deg[i] + 1));   // +1 = self-loop
}

__global__ void scanA_kernel(const int* __restrict__ deg, int* __restrict__ rowptr,
                             int* __restrict__ bsum, int N){
  __shared__ int sd[BLK];
  int tid = threadIdx.x;
  int base = blockIdx.x * SCAN_CHUNK;
  int vals[4]; int tsum = 0;
  #pragma unroll
  for (int q=0;q<4;q++){
    int idx = base + tid*4 + q;
    int v = (idx < N) ? (deg[idx] + 1) : 0;
    vals[q] = v; tsum += v;
  }
  sd[tid] = tsum; __syncthreads();
  for (int off=1; off<BLK; off<<=1){
    int v = (tid >= off) ? sd[tid-off] : 0;
    __syncthreads();
    sd[tid] += v;
    __syncthreads();
  }
  int run = sd[tid] - tsum;
  #pragma unroll
  for (int q=0;q<4;q++){
    run += vals[q];
    int idx = base + tid*4 + q;
    if (idx < N) rowptr[idx+1] = run;
  }
  if (tid == BLK-1) bsum[blockIdx.x] = sd[BLK-1];
}

__global__ void scanB_kernel(int* bsum, int B){
  __shared__ int sd[BLK];
  int tid = threadIdx.x;
  int v0 = (tid < B) ? bsum[tid] : 0;
  sd[tid] = v0; __syncthreads();
  for (int off=1; off<BLK; off<<=1){
    int v = (tid>=off) ? sd[tid-off] : 0;
    __syncthreads();
    sd[tid] += v;
    __syncthreads();
  }
  if (tid < B) bsum[tid] = sd[tid] - v0;
}

__global__ void scanC_kernel(int* rowptr, const int* __restrict__ bsum, int N){
  int i = blockIdx.x*blockDim.x + threadIdx.x;
  if (i == 0) rowptr[0] = 0;
  if (i < N) rowptr[i+1] += bsum[i / SCAN_CHUNK];
}

// atomic-free scatter: col only (4B/edge), weights folded into node features
__global__ void fill_kernel(const int* __restrict__ src, const int* __restrict__ dst,
                            const int* __restrict__ eslot, const int* __restrict__ rowptr,
                            const int* __restrict__ deg, int* __restrict__ col, int E, int N){
  int t = blockIdx.x*blockDim.x + threadIdx.x;
  if (t < E){
    int d = dst[t];
    col[rowptr[d] + eslot[t]] = src[t];
  } else if (t < E + N){
    int d = t - E;
    col[rowptr[d] + deg[d]] = d;   // self-loop in last slot
  }
}

// ---------------- W1 transpose+cvt: [256][128] fp32 -> [128][256] bf16 ----------------

__global__ void wcvt_kernel(const float* __restrict__ W1, unsigned short* __restrict__ W1T){
  int t = blockIdx.x*blockDim.x + threadIdx.x;
  if (t < 256*128){
    int k = t >> 7, n = t & 127;
    W1T[n*256 + k] = f2b(W1[t]);
  }
}

// ---------------- GEMM1 (MFMA bf16): h1b[r] = dinv[r] * (x @ W1)[r], bf16 ----------------

#define XPAD 40   // bf16 elements per LDS row (32 + 8 pad): 80B row stride (16B-multiple)

__global__ __launch_bounds__(256)
void gemm1_mfma(const float* __restrict__ X, const unsigned short* __restrict__ W1T,
                const float* __restrict__ dinv, unsigned short* __restrict__ H1B, int M){
  __shared__ __attribute__((aligned(16))) unsigned short xs[128*XPAD];   // [m][k]
  __shared__ __attribute__((aligned(16))) unsigned short wt[128*XPAD];   // [n][k]
  const int tid = threadIdx.x;
  const int wave = tid >> 6, lane = tid & 63;
  const int quad = lane >> 4, l16 = lane & 15;
  const int row0 = blockIdx.x * 128;

  f32x4 acc[2][8];
  #pragma unroll
  for (int i=0;i<2;i++)
    #pragma unroll
    for (int j=0;j<8;j++) acc[i][j] = (f32x4){0.f,0.f,0.f,0.f};

  const int r    = tid >> 1;
  const int half = tid & 1;

  for (int k0 = 0; k0 < 256; k0 += 32){
    {
      int gr = row0 + r;
      const float* xp = X + (size_t)gr*256 + k0 + half*16;
      unsigned short* xd = xs + r*XPAD + half*16;
      #pragma unroll
      for (int q=0;q<4;q++){
        float4 v = (gr < M) ? *(const float4*)(xp + q*4) : make_float4(0.f,0.f,0.f,0.f);
        ushort4 b;
        b.x = f2b(v.x); b.y = f2b(v.y); b.z = f2b(v.z); b.w = f2b(v.w);
        *(ushort4*)(xd + q*4) = b;
      }
    }
    {
      const unsigned short* wp = W1T + r*256 + k0 + half*16;
      unsigned short* wd = wt + r*XPAD + half*16;
      uint4 a = *(const uint4*)wp;
      uint4 c = *(const uint4*)(wp + 8);
      *(uint4*)wd = a;
      *(uint4*)(wd + 8) = c;
    }
    __syncthreads();

    bf16x8 bfr[8];
    #pragma unroll
    for (int ct=0; ct<8; ct++)
      bfr[ct] = *(bf16x8*)(wt + (ct*16 + l16)*XPAD + quad*8);
    #pragma unroll
    for (int rt=0; rt<2; rt++){
      bf16x8 a = *(bf16x8*)(xs + (wave*32 + rt*16 + l16)*XPAD + quad*8);
      #pragma unroll
      for (int ct=0; ct<8; ct++)
        acc[rt][ct] = __builtin_amdgcn_mfma_f32_16x16x32_bf16(a, bfr[ct], acc[rt][ct], 0, 0, 0);
    }
    __syncthreads();
  }

  #pragma unroll
  for (int rt=0; rt<2; rt++){
    int rbase = row0 + wave*32 + rt*16 + quad*4;
    #pragma unroll
    for (int rg=0; rg<4; rg++){
      int grow = rbase + rg;
      if (grow < M){
        float dv = dinv[grow];
        #pragma unroll
        for (int ct=0; ct<8; ct++)
          H1B[(size_t)grow*128 + ct*16 + l16] = f2b(dv * acc[rt][ct][rg]);
      }
    }
  }
}

// ---------------- agg1: wave/node gather (4-wide) + dinv scale + bias + ReLU -> bf16 r1 ----------------

__global__ __launch_bounds__(256)
void agg1_kernel(const unsigned short* __restrict__ H1B, const int* __restrict__ rowptr,
                 const int* __restrict__ col, const float* __restrict__ dinv,
                 const float* __restrict__ b1, unsigned int* __restrict__ R1B, int N){
  int node = blockIdx.x * 4 + (threadIdx.x >> 6);
  int lane = threadIdx.x & 63;
  if (node >= N) return;
  int s = rowptr[node], e = rowptr[node+1];
  float a0=0.f,a1=0.f,b0=0.f,b1v=0.f,c0=0.f,c1=0.f,d0=0.f,d1=0.f;
  int j = s;
  for (; j+3 < e; j += 4){
    int cA = col[j], cB = col[j+1], cC = col[j+2], cD = col[j+3];
    unsigned uA = *(const unsigned*)(H1B + (size_t)cA*128 + lane*2);
    unsigned uB = *(const unsigned*)(H1B + (size_t)cB*128 + lane*2);
    unsigned uC = *(const unsigned*)(H1B + (size_t)cC*128 + lane*2);
    unsigned uD = *(const unsigned*)(H1B + (size_t)cD*128 + lane*2);
    a0 += b2f_lo(uA); a1 += b2f_hi(uA);
    b0 += b2f_lo(uB); b1v+= b2f_hi(uB);
    c0 += b2f_lo(uC); c1 += b2f_hi(uC);
    d0 += b2f_lo(uD); d1 += b2f_hi(uD);
  }
  for (; j < e; j++){
    int cA = col[j];
    unsigned uA = *(const unsigned*)(H1B + (size_t)cA*128 + lane*2);
    a0 += b2f_lo(uA); a1 += b2f_hi(uA);
  }
  float dv = dinv[node];
  float acc0 = (a0+b0)+(c0+d0);
  float acc1 = (a1+b1v)+(c1+d1);
  float r0 = fmaxf(dv*acc0 + b1[lane*2],     0.f);
  float r1 = fmaxf(dv*acc1 + b1[lane*2 + 1], 0.f);
  R1B[(size_t)node*64 + lane] = (unsigned)f2b(r0) | ((unsigned)f2b(r1) << 16);
}

// ---------------- GEMM2: h2[r] = dinv[r] * (r1[r] @ W2), fp32 [M,12] ----------------

__global__ __launch_bounds__(256)
void gemm2_kernel(const unsigned int* __restrict__ R1B, const float* __restrict__ W2,
                  const float* __restrict__ dinv, float* __restrict__ H2, int M){
  __shared__ float w2s[128*10];   // wave-uniform reads -> broadcast, no conflicts
  for (int i = threadIdx.x; i < 128*10; i += blockDim.x) w2s[i] = W2[i];
  __syncthreads();
  int r = blockIdx.x*blockDim.x + threadIdx.x;
  if (r >= M) return;
  float acc[10];
  #pragma unroll
  for (int c=0;c<10;c++) acc[c] = 0.f;
  const unsigned int* row = R1B + (size_t)r*64;
  for (int k=0;k<64;k+=4){
    uint4 u = *(const uint4*)(row + k);
    float f0 = b2f_lo(u.x), f1 = b2f_hi(u.x);
    float f2 = b2f_lo(u.y), f3 = b2f_hi(u.y);
    float f4 = b2f_lo(u.z), f5 = b2f_hi(u.z);
    float f6 = b2f_lo(u.w), f7 = b2f_hi(u.w);
    #pragma unroll
    for (int c=0;c<10;c++){
      acc[c] += f0*w2s[(2*k+0)*10+c] + f1*w2s[(2*k+1)*10+c]
              + f2*w2s[(2*k+2)*10+c] + f3*w2s[(2*k+3)*10+c]
              + f4*w2s[(2*k+4)*10+c] + f5*w2s[(2*k+5)*10+c]
              + f6*w2s[(2*k+6)*10+c] + f7*w2s[(2*k+7)*10+c];
    }
  }
  float dv = dinv[r];
  float4* op = (float4*)(H2 + (size_t)r*12);
  op[0] = make_float4(dv*acc[0],dv*acc[1],dv*acc[2],dv*acc[3]);
  op[1] = make_float4(dv*acc[4],dv*acc[5],dv*acc[6],dv*acc[7]);
  op[2] = make_float4(dv*acc[8],dv*acc[9],0.f,0.f);
}

// ---------------- agg2 + dinv scale + bias + log_softmax (2-wide) ----------------

__global__ __launch_bounds__(256)
void agg2_softmax_kernel(const float* __restrict__ H2, const int* __restrict__ rowptr,
                         const int* __restrict__ col, const float* __restrict__ dinv,
                         const float* __restrict__ b2, float* __restrict__ out, int N){
  int i = blockIdx.x*blockDim.x + threadIdx.x;
  if (i >= N) return;
  float acc[10], acc2[10];
  #pragma unroll
  for (int c=0;c<10;c++){ acc[c] = 0.f; acc2[c] = 0.f; }
  int s = rowptr[i], e = rowptr[i+1];
  int j = s;
  for (; j+1 < e; j += 2){
    int cA = col[j], cB = col[j+1];
    const float4* hA = (const float4*)(H2 + (size_t)cA*12);
    const float4* hB = (const float4*)(H2 + (size_t)cB*12);
    float4 a0 = hA[0], a1 = hA[1], a2 = hA[2];
    float4 bq0 = hB[0], bq1 = hB[1], bq2 = hB[2];
    acc[0]+=a0.x; acc[1]+=a0.y; acc[2]+=a0.z; acc[3]+=a0.w;
    acc[4]+=a1.x; acc[5]+=a1.y; acc[6]+=a1.z; acc[7]+=a1.w;
    acc[8]+=a2.x; acc[9]+=a2.y;
    acc2[0]+=bq0.x; acc2[1]+=bq0.y; acc2[2]+=bq0.z; acc2[3]+=bq0.w;
    acc2[4]+=bq1.x; acc2[5]+=bq1.y; acc2[6]+=bq1.z; acc2[7]+=bq1.w;
    acc2[8]+=bq2.x; acc2[9]+=bq2.y;
  }
  if (j < e){
    int cA = col[j];
    const float4* h = (const float4*)(H2 + (size_t)cA*12);
    float4 v0 = h[0], v1 = h[1], v2 = h[2];
    acc[0]+=v0.x; acc[1]+=v0.y; acc[2]+=v0.z; acc[3]+=v0.w;
    acc[4]+=v1.x; acc[5]+=v1.y; acc[6]+=v1.z; acc[7]+=v1.w;
    acc[8]+=v2.x; acc[9]+=v2.y;
  }
  float dv = dinv[i];
  #pragma unroll
  for (int f=0;f<10;f++) acc[f] = dv*(acc[f] + acc2[f]) + b2[f];
  float m = acc[0];
  #pragma unroll
  for (int f=1;f<10;f++) m = fmaxf(m, acc[f]);
  float sum = 0.f;
  #pragma unroll
  for (int f=0;f<10;f++) sum += expf(acc[f] - m);
  float lg = m + logf(sum);
  #pragma unroll
  for (int f=0;f<10;f++) out[(size_t)i*10 + f] = acc[f] - lg;
}

// ---------------- launch ----------------

extern "C" void kernel_launch(void* const* d_in, const int* in_sizes, int n_in,
                              void* d_out, int out_size, void* d_ws, size_t ws_size,
                              hipStream_t stream){
  const float* x    = (const float*)d_in[0];
  const int*   ei   = (const int*)d_in[1];
  const float* W1   = (const float*)d_in[2];
  const float* b1   = (const float*)d_in[3];
  const float* W2   = (const float*)d_in[4];
  const float* b2   = (const float*)d_in[5];
  float* out = (float*)d_out;

  const int N = in_sizes[0] / 256;   // 100000
  const int E = in_sizes[1] / 2;     // 1600000
  const int NNZ = E + N;
  const int* src = ei;
  const int* dst = ei + E;

  char* ws = (char*)d_ws;
  size_t off = 0;
  auto alloc = [&](size_t bytes)->char*{
    char* p = ws + off;
    off = (off + bytes + 255) & ~(size_t)255;
    return p;
  };
  int*   deg    = (int*)  alloc((size_t)N*4);
  int*   eslot  = (int*)  alloc((size_t)E*4);
  float* dinv   = (float*)alloc((size_t)N*4);
  int*   rowptr = (int*)  alloc((size_t)(N+1)*4);
  int*   bsum   = (int*)  alloc((size_t)BLK*4);
  int*   col    = (int*)  alloc((size_t)NNZ*4);
  unsigned short* w1t = (unsigned short*)alloc((size_t)128*256*2);
  unsigned short* h1b = (unsigned short*)alloc((size_t)N*128*2);
  unsigned int*   r1b = (unsigned int*)  alloc((size_t)N*64*4);
  float* h2     = (float*)alloc((size_t)N*12*4);
  (void)ws_size;

  hipMemsetAsync(deg, 0, (size_t)N*4, stream);

  const int B = (N + SCAN_CHUNK - 1) / SCAN_CHUNK;

  count_deg_kernel<<<(E+BLK-1)/BLK, BLK, 0, stream>>>(dst, deg, eslot, E);
  dinv_kernel<<<(N+BLK-1)/BLK, BLK, 0, stream>>>(deg, dinv, N);
  scanA_kernel<<<B, BLK, 0, stream>>>(deg, rowptr, bsum, N);
  scanB_kernel<<<1, BLK, 0, stream>>>(bsum, B);
  scanC_kernel<<<(N+BLK-1)/BLK, BLK, 0, stream>>>(rowptr, bsum, N);
  fill_kernel<<<(NNZ+BLK-1)/BLK, BLK, 0, stream>>>(src, dst, eslot, rowptr, deg, col, E, N);
  wcvt_kernel<<<(256*128+BLK-1)/BLK, BLK, 0, stream>>>(W1, w1t);

  gemm1_mfma<<<(N+127)/128, 256, 0, stream>>>(x, w1t, dinv, h1b, N);
  agg1_kernel<<<(N+3)/4, 256, 0, stream>>>(h1b, rowptr, col, dinv, b1, r1b, N);
  gemm2_kernel<<<(N+BLK-1)/BLK, BLK, 0, stream>>>(r1b, W2, dinv, h2, N);
  agg2_softmax_kernel<<<(N+BLK-1)/BLK, BLK, 0, stream>>>(h2, rowptr, col, dinv, b2, out, N);
}

// Round 6
// 395.912 us; speedup vs baseline: 1.7029x; 1.0573x over previous
//
#include <hip/hip_runtime.h>
#include <math.h>

#define BLK 256
#define SCAN_CHUNK 1024

// bucketed CSR build: 512 dst-nodes per bucket
#define BKT_BITS 9
#define BKT (1<<BKT_BITS)
#define MAXNB 256
#define EB 8192   // edges per bin-block

typedef __attribute__((ext_vector_type(8))) short bf16x8;
typedef __attribute__((ext_vector_type(4))) float f32x4;

__device__ inline unsigned short f2b(float f){
  union { float f; unsigned int u; } v; v.f = f;
  unsigned int u = v.u;
  return (unsigned short)((u + 0x7FFF + ((u >> 16) & 1)) >> 16);
}
__device__ inline float b2f_lo(unsigned int u){
  union { unsigned int u; float f; } v; v.u = u << 16; return v.f;
}
__device__ inline float b2f_hi(unsigned int u){
  union { unsigned int u; float f; } v; v.u = u & 0xFFFF0000u; return v.f;
}

// ---------------- bucketed CSR build ----------------

// A: bucket histogram (LDS-first, ~200 global atomics/block)
__global__ __launch_bounds__(256)
void bhistA(const int* __restrict__ dst, int* __restrict__ bhist, int E, int NB){
  __shared__ int h[MAXNB];
  int t = threadIdx.x;
  for (int i=t;i<NB;i+=256) h[i]=0;
  __syncthreads();
  int base = blockIdx.x*EB;
  #pragma unroll
  for (int k=0;k<EB/256;k++){
    int idx = base + k*256 + t;
    if (idx < E) atomicAdd(&h[dst[idx]>>BKT_BITS], 1);
  }
  __syncthreads();
  for (int i=t;i<NB;i+=256) if (h[i]) atomicAdd(&bhist[i], h[i]);
}

// B: scan bucket counts -> boffs, init bucket cursors
__global__ void bscanB(const int* __restrict__ bhist, int* __restrict__ boffs,
                       int* __restrict__ bcur, int NB){
  __shared__ int h[MAXNB];
  int t = threadIdx.x;
  int v0 = (t < NB) ? bhist[t] : 0;
  h[t] = v0; __syncthreads();
  for (int off=1; off<MAXNB; off<<=1){
    int v = (t>=off)?h[t-off]:0;
    __syncthreads();
    h[t]+=v;
    __syncthreads();
  }
  if (t<NB){ int excl=h[t]-v0; boffs[t]=excl; bcur[t]=excl; }
}

// C: bin edges into buckets via LDS sort; full-line coalesced run writes
__global__ __launch_bounds__(256)
void binC(const int* __restrict__ src, const int* __restrict__ dst, int* __restrict__ bcur,
          int2* __restrict__ bins, int E, int NB){
  __shared__ int lh[MAXNB];
  __shared__ int lofs[MAXNB];
  __shared__ int lcur[MAXNB];
  __shared__ int gres[MAXNB];
  __shared__ __attribute__((aligned(16))) int2 buf[EB];
  int t = threadIdx.x;
  for (int i=t;i<NB;i+=256) lh[i]=0;
  __syncthreads();
  int base = blockIdx.x*EB;
  // pass 1: local bucket counts
  #pragma unroll
  for (int k=0;k<EB/256;k++){
    int idx = base + k*256 + t;
    if (idx < E) atomicAdd(&lh[dst[idx]>>BKT_BITS], 1);
  }
  __syncthreads();
  if (t==0){ int run=0; for (int b=0;b<NB;b++){ lofs[b]=run; run+=lh[b]; } }
  __syncthreads();
  if (t<NB){
    lcur[t] = lofs[t];
    gres[t] = lh[t] ? atomicAdd(&bcur[t], lh[t]) : 0;
  }
  __syncthreads();
  // pass 2: scatter pairs into LDS sorted-by-bucket order
  #pragma unroll
  for (int k=0;k<EB/256;k++){
    int idx = base + k*256 + t;
    if (idx < E){
      int d = dst[idx];
      int p = atomicAdd(&lcur[d>>BKT_BITS], 1);
      buf[p] = make_int2(src[idx], d);
    }
  }
  __syncthreads();
  // copy out: consecutive i -> same-bucket runs -> coalesced global writes
  int total = E - base; if (total > EB) total = EB;
  for (int i=t; i<total; i+=256){
    int2 pr = buf[i];
    int b = pr.y>>BKT_BITS;
    bins[gres[b] + (i - lofs[b])] = pr;
  }
}

// D: per-node degree from bucket pairs (LDS counters, coalesced deg write)
__global__ __launch_bounds__(256)
void bdegD(const int2* __restrict__ bins, const int* __restrict__ boffs,
           const int* __restrict__ bhist, int* __restrict__ deg, int N){
  __shared__ int dcnt[BKT];
  int b = blockIdx.x;
  for (int i=threadIdx.x;i<BKT;i+=256) dcnt[i]=0;
  __syncthreads();
  int s = boffs[b], cnt = bhist[b];
  for (int i=threadIdx.x;i<cnt;i+=256)
    atomicAdd(&dcnt[bins[s+i].y & (BKT-1)], 1);
  __syncthreads();
  int base = b<<BKT_BITS;
  for (int i=threadIdx.x;i<BKT;i+=256){
    int node = base+i;
    if (node < N) deg[node] = dcnt[i];
  }
}

__global__ void dinv_kernel(const int* __restrict__ deg, float* __restrict__ dinv, int N){
  int i = blockIdx.x*blockDim.x + threadIdx.x;
  if (i < N) dinv[i] = rsqrtf((float)(deg[i] + 1));   // +1 = self-loop
}

__global__ void scanA_kernel(const int* __restrict__ deg, int* __restrict__ rowptr,
                             int* __restrict__ bsum, int N){
  __shared__ int sd[BLK];
  int tid = threadIdx.x;
  int base = blockIdx.x * SCAN_CHUNK;
  int vals[4]; int tsum = 0;
  #pragma unroll
  for (int q=0;q<4;q++){
    int idx = base + tid*4 + q;
    int v = (idx < N) ? (deg[idx] + 1) : 0;
    vals[q] = v; tsum += v;
  }
  sd[tid] = tsum; __syncthreads();
  for (int off=1; off<BLK; off<<=1){
    int v = (tid >= off) ? sd[tid-off] : 0;
    __syncthreads();
    sd[tid] += v;
    __syncthreads();
  }
  int run = sd[tid] - tsum;
  #pragma unroll
  for (int q=0;q<4;q++){
    run += vals[q];
    int idx = base + tid*4 + q;
    if (idx < N) rowptr[idx+1] = run;
  }
  if (tid == BLK-1) bsum[blockIdx.x] = sd[BLK-1];
}

__global__ void scanB_kernel(int* bsum, int B){
  __shared__ int sd[BLK];
  int tid = threadIdx.x;
  int v0 = (tid < B) ? bsum[tid] : 0;
  sd[tid] = v0; __syncthreads();
  for (int off=1; off<BLK; off<<=1){
    int v = (tid>=off) ? sd[tid-off] : 0;
    __syncthreads();
    sd[tid] += v;
    __syncthreads();
  }
  if (tid < B) bsum[tid] = sd[tid] - v0;
}

__global__ void scanC_kernel(int* rowptr, const int* __restrict__ bsum, int N){
  int i = blockIdx.x*blockDim.x + threadIdx.x;
  if (i == 0) rowptr[0] = 0;
  if (i < N) rowptr[i+1] += bsum[i / SCAN_CHUNK];
}

// F: per-bucket CSR fill — LDS cursors only, single-CU full-line col writes
__global__ __launch_bounds__(256)
void bfillF(const int2* __restrict__ bins, const int* __restrict__ boffs,
            const int* __restrict__ bhist, const int* __restrict__ rowptr,
            int* __restrict__ col, int N){
  __shared__ int rp[BKT];
  __shared__ int cur[BKT];
  int b = blockIdx.x;
  int base = b<<BKT_BITS;
  for (int i=threadIdx.x;i<BKT;i+=256){
    int node = base+i;
    rp[i] = (node < N) ? rowptr[node] : 0;
    cur[i] = 0;
  }
  __syncthreads();
  int s = boffs[b], cnt = bhist[b];
  for (int i=threadIdx.x;i<cnt;i+=256){
    int2 pr = bins[s+i];
    int ln = pr.y & (BKT-1);
    int slot = atomicAdd(&cur[ln], 1);
    col[rp[ln] + slot] = pr.x;
  }
  __syncthreads();
  for (int i=threadIdx.x;i<BKT;i+=256){
    int node = base+i;
    if (node < N) col[rp[i] + cur[i]] = node;   // self-loop in last slot
  }
}

// ---------------- W1 transpose+cvt: [256][128] fp32 -> [128][256] bf16 ----------------

__global__ void wcvt_kernel(const float* __restrict__ W1, unsigned short* __restrict__ W1T){
  int t = blockIdx.x*blockDim.x + threadIdx.x;
  if (t < 256*128){
    int k = t >> 7, n = t & 127;
    W1T[n*256 + k] = f2b(W1[t]);
  }
}

// ---------------- GEMM1 (MFMA bf16): h1b[r] = dinv[r] * (x @ W1)[r], bf16 ----------------

#define XPAD 40   // bf16 elements per LDS row (32 + 8 pad): 80B row stride (16B-multiple)

__global__ __launch_bounds__(256)
void gemm1_mfma(const float* __restrict__ X, const unsigned short* __restrict__ W1T,
                const float* __restrict__ dinv, unsigned short* __restrict__ H1B, int M){
  __shared__ __attribute__((aligned(16))) unsigned short xs[128*XPAD];   // [m][k]
  __shared__ __attribute__((aligned(16))) unsigned short wt[128*XPAD];   // [n][k]
  const int tid = threadIdx.x;
  const int wave = tid >> 6, lane = tid & 63;
  const int quad = lane >> 4, l16 = lane & 15;
  const int row0 = blockIdx.x * 128;

  f32x4 acc[2][8];
  #pragma unroll
  for (int i=0;i<2;i++)
    #pragma unroll
    for (int j=0;j<8;j++) acc[i][j] = (f32x4){0.f,0.f,0.f,0.f};

  const int r    = tid >> 1;
  const int half = tid & 1;

  for (int k0 = 0; k0 < 256; k0 += 32){
    {
      int gr = row0 + r;
      const float* xp = X + (size_t)gr*256 + k0 + half*16;
      unsigned short* xd = xs + r*XPAD + half*16;
      #pragma unroll
      for (int q=0;q<4;q++){
        float4 v = (gr < M) ? *(const float4*)(xp + q*4) : make_float4(0.f,0.f,0.f,0.f);
        ushort4 b;
        b.x = f2b(v.x); b.y = f2b(v.y); b.z = f2b(v.z); b.w = f2b(v.w);
        *(ushort4*)(xd + q*4) = b;
      }
    }
    {
      const unsigned short* wp = W1T + r*256 + k0 + half*16;
      unsigned short* wd = wt + r*XPAD + half*16;
      uint4 a = *(const uint4*)wp;
      uint4 c = *(const uint4*)(wp + 8);
      *(uint4*)wd = a;
      *(uint4*)(wd + 8) = c;
    }
    __syncthreads();

    bf16x8 bfr[8];
    #pragma unroll
    for (int ct=0; ct<8; ct++)
      bfr[ct] = *(bf16x8*)(wt + (ct*16 + l16)*XPAD + quad*8);
    #pragma unroll
    for (int rt=0; rt<2; rt++){
      bf16x8 a = *(bf16x8*)(xs + (wave*32 + rt*16 + l16)*XPAD + quad*8);
      #pragma unroll
      for (int ct=0; ct<8; ct++)
        acc[rt][ct] = __builtin_amdgcn_mfma_f32_16x16x32_bf16(a, bfr[ct], acc[rt][ct], 0, 0, 0);
    }
    __syncthreads();
  }

  #pragma unroll
  for (int rt=0; rt<2; rt++){
    int rbase = row0 + wave*32 + rt*16 + quad*4;
    #pragma unroll
    for (int rg=0; rg<4; rg++){
      int grow = rbase + rg;
      if (grow < M){
        float dv = dinv[grow];
        #pragma unroll
        for (int ct=0; ct<8; ct++)
          H1B[(size_t)grow*128 + ct*16 + l16] = f2b(dv * acc[rt][ct][rg]);
      }
    }
  }
}

// ---------------- agg1: wave/node gather (4-wide) + dinv scale + bias + ReLU -> bf16 r1 ----------------

__global__ __launch_bounds__(256)
void agg1_kernel(const unsigned short* __restrict__ H1B, const int* __restrict__ rowptr,
                 const int* __restrict__ col, const float* __restrict__ dinv,
                 const float* __restrict__ b1, unsigned int* __restrict__ R1B, int N){
  int node = blockIdx.x * 4 + (threadIdx.x >> 6);
  int lane = threadIdx.x & 63;
  if (node >= N) return;
  int s = rowptr[node], e = rowptr[node+1];
  float a0=0.f,a1=0.f,b0=0.f,b1v=0.f,c0=0.f,c1=0.f,d0=0.f,d1=0.f;
  int j = s;
  for (; j+3 < e; j += 4){
    int cA = col[j], cB = col[j+1], cC = col[j+2], cD = col[j+3];
    unsigned uA = *(const unsigned*)(H1B + (size_t)cA*128 + lane*2);
    unsigned uB = *(const unsigned*)(H1B + (size_t)cB*128 + lane*2);
    unsigned uC = *(const unsigned*)(H1B + (size_t)cC*128 + lane*2);
    unsigned uD = *(const unsigned*)(H1B + (size_t)cD*128 + lane*2);
    a0 += b2f_lo(uA); a1 += b2f_hi(uA);
    b0 += b2f_lo(uB); b1v+= b2f_hi(uB);
    c0 += b2f_lo(uC); c1 += b2f_hi(uC);
    d0 += b2f_lo(uD); d1 += b2f_hi(uD);
  }
  for (; j < e; j++){
    int cA = col[j];
    unsigned uA = *(const unsigned*)(H1B + (size_t)cA*128 + lane*2);
    a0 += b2f_lo(uA); a1 += b2f_hi(uA);
  }
  float dv = dinv[node];
  float acc0 = (a0+b0)+(c0+d0);
  float acc1 = (a1+b1v)+(c1+d1);
  float r0 = fmaxf(dv*acc0 + b1[lane*2],     0.f);
  float r1 = fmaxf(dv*acc1 + b1[lane*2 + 1], 0.f);
  R1B[(size_t)node*64 + lane] = (unsigned)f2b(r0) | ((unsigned)f2b(r1) << 16);
}

// ---------------- GEMM2: h2[r] = dinv[r] * (r1[r] @ W2), fp32 [M,12] ----------------

__global__ __launch_bounds__(256)
void gemm2_kernel(const unsigned int* __restrict__ R1B, const float* __restrict__ W2,
                  const float* __restrict__ dinv, float* __restrict__ H2, int M){
  __shared__ float w2s[128*10];   // wave-uniform reads -> broadcast, no conflicts
  for (int i = threadIdx.x; i < 128*10; i += blockDim.x) w2s[i] = W2[i];
  __syncthreads();
  int r = blockIdx.x*blockDim.x + threadIdx.x;
  if (r >= M) return;
  float acc[10];
  #pragma unroll
  for (int c=0;c<10;c++) acc[c] = 0.f;
  const unsigned int* row = R1B + (size_t)r*64;
  for (int k=0;k<64;k+=4){
    uint4 u = *(const uint4*)(row + k);
    float f0 = b2f_lo(u.x), f1 = b2f_hi(u.x);
    float f2 = b2f_lo(u.y), f3 = b2f_hi(u.y);
    float f4 = b2f_lo(u.z), f5 = b2f_hi(u.z);
    float f6 = b2f_lo(u.w), f7 = b2f_hi(u.w);
    #pragma unroll
    for (int c=0;c<10;c++){
      acc[c] += f0*w2s[(2*k+0)*10+c] + f1*w2s[(2*k+1)*10+c]
              + f2*w2s[(2*k+2)*10+c] + f3*w2s[(2*k+3)*10+c]
              + f4*w2s[(2*k+4)*10+c] + f5*w2s[(2*k+5)*10+c]
              + f6*w2s[(2*k+6)*10+c] + f7*w2s[(2*k+7)*10+c];
    }
  }
  float dv = dinv[r];
  float4* op = (float4*)(H2 + (size_t)r*12);
  op[0] = make_float4(dv*acc[0],dv*acc[1],dv*acc[2],dv*acc[3]);
  op[1] = make_float4(dv*acc[4],dv*acc[5],dv*acc[6],dv*acc[7]);
  op[2] = make_float4(dv*acc[8],dv*acc[9],0.f,0.f);
}

// ---------------- agg2 + dinv scale + bias + log_softmax (2-wide) ----------------

__global__ __launch_bounds__(256)
void agg2_softmax_kernel(const float* __restrict__ H2, const int* __restrict__ rowptr,
                         const int* __restrict__ col, const float* __restrict__ dinv,
                         const float* __restrict__ b2, float* __restrict__ out, int N){
  int i = blockIdx.x*blockDim.x + threadIdx.x;
  if (i >= N) return;
  float acc[10], acc2[10];
  #pragma unroll
  for (int c=0;c<10;c++){ acc[c] = 0.f; acc2[c] = 0.f; }
  int s = rowptr[i], e = rowptr[i+1];
  int j = s;
  for (; j+1 < e; j += 2){
    int cA = col[j], cB = col[j+1];
    const float4* hA = (const float4*)(H2 + (size_t)cA*12);
    const float4* hB = (const float4*)(H2 + (size_t)cB*12);
    float4 a0 = hA[0], a1 = hA[1], a2 = hA[2];
    float4 bq0 = hB[0], bq1 = hB[1], bq2 = hB[2];
    acc[0]+=a0.x; acc[1]+=a0.y; acc[2]+=a0.z; acc[3]+=a0.w;
    acc[4]+=a1.x; acc[5]+=a1.y; acc[6]+=a1.z; acc[7]+=a1.w;
    acc[8]+=a2.x; acc[9]+=a2.y;
    acc2[0]+=bq0.x; acc2[1]+=bq0.y; acc2[2]+=bq0.z; acc2[3]+=bq0.w;
    acc2[4]+=bq1.x; acc2[5]+=bq1.y; acc2[6]+=bq1.z; acc2[7]+=bq1.w;
    acc2[8]+=bq2.x; acc2[9]+=bq2.y;
  }
  if (j < e){
    int cA = col[j];
    const float4* h = (const float4*)(H2 + (size_t)cA*12);
    float4 v0 = h[0], v1 = h[1], v2 = h[2];
    acc[0]+=v0.x; acc[1]+=v0.y; acc[2]+=v0.z; acc[3]+=v0.w;
    acc[4]+=v1.x; acc[5]+=v1.y; acc[6]+=v1.z; acc[7]+=v1.w;
    acc[8]+=v2.x; acc[9]+=v2.y;
  }
  float dv = dinv[i];
  #pragma unroll
  for (int f=0;f<10;f++) acc[f] = dv*(acc[f] + acc2[f]) + b2[f];
  float m = acc[0];
  #pragma unroll
  for (int f=1;f<10;f++) m = fmaxf(m, acc[f]);
  float sum = 0.f;
  #pragma unroll
  for (int f=0;f<10;f++) sum += expf(acc[f] - m);
  float lg = m + logf(sum);
  #pragma unroll
  for (int f=0;f<10;f++) out[(size_t)i*10 + f] = acc[f] - lg;
}

// ---------------- launch ----------------

extern "C" void kernel_launch(void* const* d_in, const int* in_sizes, int n_in,
                              void* d_out, int out_size, void* d_ws, size_t ws_size,
                              hipStream_t stream){
  const float* x    = (const float*)d_in[0];
  const int*   ei   = (const int*)d_in[1];
  const float* W1   = (const float*)d_in[2];
  const float* b1   = (const float*)d_in[3];
  const float* W2   = (const float*)d_in[4];
  const float* b2   = (const float*)d_in[5];
  float* out = (float*)d_out;

  const int N = in_sizes[0] / 256;   // 100000
  const int E = in_sizes[1] / 2;     // 1600000
  const int NNZ = E + N;
  const int* src = ei;
  const int* dst = ei + E;
  const int NB = (N + BKT - 1) >> BKT_BITS;   // 196

  char* ws = (char*)d_ws;
  size_t off = 0;
  auto alloc = [&](size_t bytes)->char*{
    char* p = ws + off;
    off = (off + bytes + 255) & ~(size_t)255;
    return p;
  };
  int*   deg    = (int*)  alloc((size_t)N*4);
  float* dinv   = (float*)alloc((size_t)N*4);
  int*   rowptr = (int*)  alloc((size_t)(N+1)*4);
  int*   bsum   = (int*)  alloc((size_t)BLK*4);
  int*   bhist  = (int*)  alloc((size_t)MAXNB*4);
  int*   boffs  = (int*)  alloc((size_t)MAXNB*4);
  int*   bcur   = (int*)  alloc((size_t)MAXNB*4);
  int2*  bins   = (int2*) alloc((size_t)E*8);
  int*   col    = (int*)  alloc((size_t)NNZ*4);
  unsigned short* w1t = (unsigned short*)alloc((size_t)128*256*2);
  unsigned short* h1b = (unsigned short*)alloc((size_t)N*128*2);
  unsigned int*   r1b = (unsigned int*)  alloc((size_t)N*64*4);
  float* h2     = (float*)alloc((size_t)N*12*4);
  (void)ws_size;

  hipMemsetAsync(bhist, 0, (size_t)MAXNB*4, stream);

  const int B   = (N + SCAN_CHUNK - 1) / SCAN_CHUNK;
  const int NCB = (E + EB - 1) / EB;

  bhistA<<<NCB, 256, 0, stream>>>(dst, bhist, E, NB);
  bscanB<<<1, MAXNB, 0, stream>>>(bhist, boffs, bcur, NB);
  binC<<<NCB, 256, 0, stream>>>(src, dst, bcur, bins, E, NB);
  bdegD<<<NB, 256, 0, stream>>>(bins, boffs, bhist, deg, N);
  dinv_kernel<<<(N+BLK-1)/BLK, BLK, 0, stream>>>(deg, dinv, N);
  scanA_kernel<<<B, BLK, 0, stream>>>(deg, rowptr, bsum, N);
  scanB_kernel<<<1, BLK, 0, stream>>>(bsum, B);
  scanC_kernel<<<(N+BLK-1)/BLK, BLK, 0, stream>>>(rowptr, bsum, N);
  bfillF<<<NB, 256, 0, stream>>>(bins, boffs, bhist, rowptr, col, N);
  wcvt_kernel<<<(256*128+BLK-1)/BLK, BLK, 0, stream>>>(W1, w1t);

  gemm1_mfma<<<(N+127)/128, 256, 0, stream>>>(x, w1t, dinv, h1b, N);
  agg1_kernel<<<(N+3)/4, 256, 0, stream>>>(h1b, rowptr, col, dinv, b1, r1b, N);
  gemm2_kernel<<<(N+BLK-1)/BLK, BLK, 0, stream>>>(r1b, W2, dinv, h2, N);
  agg2_softmax_kernel<<<(N+BLK-1)/BLK, BLK, 0, stream>>>(h2, rowptr, col, dinv, b2, out, N);
}